// Round 21
// baseline (122.983 us; speedup 1.0000x reference)
//
#include <hip/hip_runtime.h>
#include <hip/hip_bf16.h>
#include <math.h>

#define T_DIM 2048
#define E_DIM 1536
#define K_DIM 1536

typedef unsigned short u16;
typedef unsigned int u32;
typedef __attribute__((ext_vector_type(8))) short bf16x8;
typedef __attribute__((ext_vector_type(4))) float f32x4;

__device__ __forceinline__ u16 f2bf(float x) {
    unsigned u = __float_as_uint(x);
    return (u16)((u + 0x7fffu + ((u >> 16) & 1u)) >> 16);
}

#define GLOAD16(gsrc, ldst)                                                              \
    __builtin_amdgcn_global_load_lds((const __attribute__((address_space(1))) u32*)(gsrc), \
                                     (__attribute__((address_space(3))) u32*)(ldst), 16, 0, 0)

// ---------------- all f32 -> bf16 conversions in ONE kernel (5 segments)
__global__ __launch_bounds__(256) void cvt_bf16_5(const float* __restrict__ s0, u16* __restrict__ d0,
                                                  const float* __restrict__ s1, u16* __restrict__ d1,
                                                  const float* __restrict__ s2, u16* __restrict__ d2,
                                                  const float* __restrict__ s3, u16* __restrict__ d3,
                                                  const float* __restrict__ s4, u16* __restrict__ d4) {
    int i = blockIdx.x * 256 + threadIdx.x;
    const float* s;
    u16* d;
    int off;
    if (i < 786432)       { s = s0; d = d0; off = i; }
    else if (i < 1376256) { s = s1; d = d1; off = i - 786432; }
    else if (i < 1671168) { s = s2; d = d2; off = i - 1376256; }
    else if (i < 1966080) { s = s3; d = d3; off = i - 1671168; }
    else                  { s = s4; d = d4; off = i - 1966080; }
    float4 v = ((const float4*)s)[off];
    ((ushort4*)d)[off] = make_ushort4(f2bf(v.x), f2bf(v.y), f2bf(v.z), f2bf(v.w));
}

// ---------------- fused QKV GEMM, 128x64 tile (768 blocks = 3/CU, balanced).
__global__ __launch_bounds__(256) void gemm_qkv_fused(const u16* __restrict__ A,
                                                      const u16* __restrict__ W,
                                                      const float* __restrict__ cosb,
                                                      const float* __restrict__ sinb,
                                                      u16* __restrict__ qb16,
                                                      u16* __restrict__ kpack,
                                                      u16* __restrict__ vpack,
                                                      float qscale) {
    const int K = K_DIM;
    __shared__ __align__(16) u16 As[128 * 64];
    __shared__ __align__(16) u16 Bs[64 * 64];
    const int tid = threadIdx.x;
    const int lane = tid & 63;
    const int wv = tid >> 6;
    const int wr = wv >> 1;
    const int wc = wv & 1;
    const int cl = lane & 15;
    const int g = lane >> 4;
    const int bm = blockIdx.y * 128;
    const int bn = blockIdx.x * 64;

    const char* Ab = (const char*)A;
    const char* Wb = (const char*)W;

    size_t a_src[4];
    int a_dst[4];
#pragma unroll
    for (int is = 0; is < 4; ++is) {
        int b = is * 4096 + wv * 1024 + lane * 16;
        int row = b >> 7;
        int wi = b & 127;
        a_src[is] = (size_t)(bm + row) * (K * 2) + (wi ^ ((row & 7) << 4));
        a_dst[is] = b;
    }
    size_t b_src[2];
    int b_dst[2];
#pragma unroll
    for (int is = 0; is < 2; ++is) {
        int b = is * 4096 + wv * 1024 + lane * 16;
        int row = b >> 7;
        int wi = b & 127;
        b_src[is] = (size_t)(bn + row) * (K * 2) + (wi ^ ((row & 7) << 4));
        b_dst[is] = b;
    }

    f32x4 acc[4][2];
#pragma unroll
    for (int mi = 0; mi < 4; ++mi)
#pragma unroll
        for (int ni = 0; ni < 2; ++ni) acc[mi][ni] = (f32x4){0.f, 0.f, 0.f, 0.f};

    for (int k0b = 0; k0b < K * 2; k0b += 128) {
#pragma unroll
        for (int is = 0; is < 4; ++is)
            GLOAD16(Ab + a_src[is] + k0b, (char*)As + a_dst[is]);
#pragma unroll
        for (int is = 0; is < 2; ++is)
            GLOAD16(Wb + b_src[is] + k0b, (char*)Bs + b_dst[is]);
        __syncthreads();
#pragma unroll
        for (int kk = 0; kk < 2; ++kk) {
            const int co = (kk * 64 + g * 16) ^ ((cl & 7) << 4);
            bf16x8 af[4], bfr[2];
#pragma unroll
            for (int mi = 0; mi < 4; ++mi)
                af[mi] = *(const bf16x8*)((const char*)As + (wr * 64 + mi * 16 + cl) * 128 + co);
#pragma unroll
            for (int ni = 0; ni < 2; ++ni)
                bfr[ni] = *(const bf16x8*)((const char*)Bs + (wc * 32 + ni * 16 + cl) * 128 + co);
#pragma unroll
            for (int mi = 0; mi < 4; ++mi)
#pragma unroll
                for (int ni = 0; ni < 2; ++ni)
                    acc[mi][ni] = __builtin_amdgcn_mfma_f32_16x16x32_bf16(af[mi], bfr[ni], acc[mi][ni], 0, 0, 0);
        }
        __syncthreads();
    }

    // ---- fused epilogue: RoPE + pack. col parity partner lives in lane^1.
    if (bn < 1536) {
#pragma unroll
        for (int mi = 0; mi < 4; ++mi)
#pragma unroll
            for (int ni = 0; ni < 2; ++ni)
#pragma unroll
                for (int r = 0; r < 4; ++r) {
                    int trow = bm + wr * 64 + mi * 16 + 4 * g + r;
                    int c = bn + wc * 32 + ni * 16 + cl;
                    float v = acc[mi][ni][r];
                    float pv = __shfl_xor(v, 1, 64);
                    int i = (c & 31) >> 1;
                    float cs = cosb[trow * 16 + i];
                    float sn = sinb[trow * 16 + i];
                    float o = v * cs + ((c & 1) ? pv * sn : -pv * sn);
                    qb16[(size_t)trow * E_DIM + c] = f2bf(o * qscale);
                }
    } else if (bn < 2304) {
#pragma unroll
        for (int mi = 0; mi < 4; ++mi)
#pragma unroll
            for (int ni = 0; ni < 2; ++ni)
#pragma unroll
                for (int r = 0; r < 4; ++r) {
                    int trow = bm + wr * 64 + mi * 16 + 4 * g + r;
                    int c = bn + wc * 32 + ni * 16 + cl;
                    float v = acc[mi][ni][r];
                    float pv = __shfl_xor(v, 1, 64);
                    int i = (c & 31) >> 1;
                    float cs = cosb[trow * 16 + i];
                    float sn = sinb[trow * 16 + i];
                    float o = v * cs + ((c & 1) ? pv * sn : -pv * sn);
                    int ck = c - 1536;
                    int m = ck >> 8;
                    int rem = ck & 255;
                    int kvhh = rem >> 5;
                    int d = rem & 31;
                    int cch = trow >> 5, st2 = (trow >> 4) & 1, colk = trow & 15;
                    size_t dstb = ((((size_t)(kvhh * 64 + cch) * 3 + m) * 2 + st2) * 16 + colk) * 32 + d;
                    kpack[dstb] = f2bf(o);
                }
    } else {
#pragma unroll
        for (int mi = 0; mi < 4; ++mi)
#pragma unroll
            for (int ni = 0; ni < 2; ++ni)
#pragma unroll
                for (int r = 0; r < 4; ++r) {
                    int trow = bm + wr * 64 + mi * 16 + 4 * g + r;
                    int c = bn + wc * 32 + ni * 16 + cl;
                    int fq = c - 2304;
                    int kvhh = fq / 96;
                    int f = fq - kvhh * 96;
                    size_t dstb = ((size_t)(kvhh * 64 + (trow >> 5)) * 96 + f) * 32 + (trow & 31);
                    vpack[dstb] = f2bf(acc[mi][ni][r]);
                }
    }
}

// ---------------- bf16 MFMA GEMM 128x64 tile (output projection)
__global__ __launch_bounds__(256) void gemm_mfma_out(const u16* __restrict__ A,
                                                     const u16* __restrict__ W,
                                                     float* __restrict__ Cp,
                                                     int K, int ldC) {
    __shared__ __align__(16) u16 As[128 * 64];
    __shared__ __align__(16) u16 Bs[64 * 64];
    const int tid = threadIdx.x;
    const int lane = tid & 63;
    const int wv = tid >> 6;
    const int wr = wv >> 1;
    const int wc = wv & 1;
    const int cl = lane & 15;
    const int g = lane >> 4;
    const int bm = blockIdx.y * 128;
    const int bn = blockIdx.x * 64;

    const char* Ab = (const char*)A;
    const char* Wb = (const char*)W;

    size_t a_src[4];
    int a_dst[4];
#pragma unroll
    for (int is = 0; is < 4; ++is) {
        int b = is * 4096 + wv * 1024 + lane * 16;
        int row = b >> 7;
        int wi = b & 127;
        a_src[is] = (size_t)(bm + row) * (K * 2) + (wi ^ ((row & 7) << 4));
        a_dst[is] = b;
    }
    size_t b_src[2];
    int b_dst[2];
#pragma unroll
    for (int is = 0; is < 2; ++is) {
        int b = is * 4096 + wv * 1024 + lane * 16;
        int row = b >> 7;
        int wi = b & 127;
        b_src[is] = (size_t)(bn + row) * (K * 2) + (wi ^ ((row & 7) << 4));
        b_dst[is] = b;
    }

    f32x4 acc[4][2];
#pragma unroll
    for (int mi = 0; mi < 4; ++mi)
#pragma unroll
        for (int ni = 0; ni < 2; ++ni) acc[mi][ni] = (f32x4){0.f, 0.f, 0.f, 0.f};

    for (int k0b = 0; k0b < K * 2; k0b += 128) {
#pragma unroll
        for (int is = 0; is < 4; ++is)
            GLOAD16(Ab + a_src[is] + k0b, (char*)As + a_dst[is]);
#pragma unroll
        for (int is = 0; is < 2; ++is)
            GLOAD16(Wb + b_src[is] + k0b, (char*)Bs + b_dst[is]);
        __syncthreads();
#pragma unroll
        for (int kk = 0; kk < 2; ++kk) {
            const int co = (kk * 64 + g * 16) ^ ((cl & 7) << 4);
            bf16x8 af[4], bfr[2];
#pragma unroll
            for (int mi = 0; mi < 4; ++mi)
                af[mi] = *(const bf16x8*)((const char*)As + (wr * 64 + mi * 16 + cl) * 128 + co);
#pragma unroll
            for (int ni = 0; ni < 2; ++ni)
                bfr[ni] = *(const bf16x8*)((const char*)Bs + (wc * 32 + ni * 16 + cl) * 128 + co);
#pragma unroll
            for (int mi = 0; mi < 4; ++mi)
#pragma unroll
                for (int ni = 0; ni < 2; ++ni)
                    acc[mi][ni] = __builtin_amdgcn_mfma_f32_16x16x32_bf16(af[mi], bfr[ni], acc[mi][ni], 0, 0, 0);
        }
        __syncthreads();
    }

#pragma unroll
    for (int mi = 0; mi < 4; ++mi)
#pragma unroll
        for (int ni = 0; ni < 2; ++ni)
#pragma unroll
            for (int r = 0; r < 4; ++r) {
                size_t row = bm + wr * 64 + mi * 16 + 4 * g + r;
                size_t col = bn + wc * 32 + ni * 16 + cl;
                Cp[row * ldC + col] = acc[mi][ni][r];
            }
}

// XCD-affinity block remap (simple LPT; quartet variant was a measured null).
__device__ __forceinline__ void attn_block_map(int lid, int& h, int& qbase) {
    int kvh8 = lid & 7;
    int rest = lid >> 3;
    h = kvh8 * 2 + (rest & 1);
    qbase = (63 - (rest >> 1)) * 32;
}

// ---------------- Pass 1: softmax denominators, QT=32 rows/block.
// facbuf layout: [(m*16 + h)][t].
__global__ __launch_bounds__(256) void attn_lsum(const u16* __restrict__ qb,
                                                 const u16* __restrict__ kpack,
                                                 const float* __restrict__ raw_map,
                                                 const float* __restrict__ wscale,
                                                 float* __restrict__ facbuf) {
    __shared__ float red1[4][3][2][16];
    const int tid = threadIdx.x;
    const int lane = tid & 63;
    const int wv = tid >> 6;
    const int col = lane & 15;
    const int g = lane >> 4;
    int h, qbase;
    attn_block_map(blockIdx.y * 64 + blockIdx.x, h, qbase);
    const int kvh = h >> 1;
    const int nfull = qbase >> 5;

    bf16x8 qfrag[3][2];
#pragma unroll
    for (int m = 0; m < 3; ++m)
#pragma unroll
        for (int q2 = 0; q2 < 2; ++q2)
            qfrag[m][q2] = *(const bf16x8*)(qb + (size_t)(qbase + 16 * q2 + col) * E_DIM + m * 512 + h * 32 + 8 * g);

    float lsum[3][2] = {{0.f, 0.f}, {0.f, 0.f}, {0.f, 0.f}};
    const int laneoff = col * 32 + 8 * g;
    const u16* kt = kpack + (size_t)(kvh * 64 + wv) * 3072;

    for (int c = wv; c < nfull; c += 4) {
        bf16x8 kf[6];
#pragma unroll
        for (int u = 0; u < 6; ++u) kf[u] = *(const bf16x8*)(kt + laneoff + u * 512);
        kt += 4 * 3072;
        __builtin_amdgcn_s_setprio(1);
#pragma unroll
        for (int m = 0; m < 3; ++m)
#pragma unroll
            for (int st = 0; st < 2; ++st)
#pragma unroll
                for (int q2 = 0; q2 < 2; ++q2) {
                    f32x4 sv = __builtin_amdgcn_mfma_f32_16x16x32_bf16(
                        kf[m * 2 + st], qfrag[m][q2], (f32x4){0.f, 0.f, 0.f, 0.f}, 0, 0, 0);
                    lsum[m][q2] += (__builtin_amdgcn_exp2f(sv[0]) + __builtin_amdgcn_exp2f(sv[1])) +
                                   (__builtin_amdgcn_exp2f(sv[2]) + __builtin_amdgcn_exp2f(sv[3]));
                }
        __builtin_amdgcn_s_setprio(0);
    }

    if ((nfull & 3) == wv) {
        const u16* ktm = kpack + (size_t)(kvh * 64 + nfull) * 3072 + laneoff;
        bf16x8 kf[6];
#pragma unroll
        for (int u = 0; u < 6; ++u) kf[u] = *(const bf16x8*)(ktm + u * 512);
#pragma unroll
        for (int m = 0; m < 3; ++m) {
            {
                f32x4 sv = __builtin_amdgcn_mfma_f32_16x16x32_bf16(
                    kf[m * 2 + 0], qfrag[m][0], (f32x4){0.f, 0.f, 0.f, 0.f}, 0, 0, 0);
#pragma unroll
                for (int r = 0; r < 4; ++r) {
                    float x = (4 * g + r > col) ? -1e30f : sv[r];
                    lsum[m][0] += __builtin_amdgcn_exp2f(x);
                }
            }
            {
                f32x4 sv = __builtin_amdgcn_mfma_f32_16x16x32_bf16(
                    kf[m * 2 + 0], qfrag[m][1], (f32x4){0.f, 0.f, 0.f, 0.f}, 0, 0, 0);
                lsum[m][1] += (__builtin_amdgcn_exp2f(sv[0]) + __builtin_amdgcn_exp2f(sv[1])) +
                              (__builtin_amdgcn_exp2f(sv[2]) + __builtin_amdgcn_exp2f(sv[3]));
            }
            {
                f32x4 sv = __builtin_amdgcn_mfma_f32_16x16x32_bf16(
                    kf[m * 2 + 1], qfrag[m][1], (f32x4){0.f, 0.f, 0.f, 0.f}, 0, 0, 0);
#pragma unroll
                for (int r = 0; r < 4; ++r) {
                    float x = (4 * g + r > col) ? -1e30f : sv[r];
                    lsum[m][1] += __builtin_amdgcn_exp2f(x);
                }
            }
        }
    }

#pragma unroll
    for (int m = 0; m < 3; ++m)
#pragma unroll
        for (int q2 = 0; q2 < 2; ++q2) {
            lsum[m][q2] += __shfl_xor(lsum[m][q2], 16, 64);
            lsum[m][q2] += __shfl_xor(lsum[m][q2], 32, 64);
        }
    if (g == 0) {
#pragma unroll
        for (int m = 0; m < 3; ++m)
#pragma unroll
            for (int q2 = 0; q2 < 2; ++q2) red1[wv][m][q2][col] = lsum[m][q2];
    }
    __syncthreads();
    if (wv == 0 && lane < 16) {
        float wsc = wscale[0];
#pragma unroll
        for (int m = 0; m < 3; ++m) {
            float mw = tanhf(raw_map[m]) * wsc;
#pragma unroll
            for (int q2 = 0; q2 < 2; ++q2) {
                float tot = red1[0][m][q2][lane] + red1[1][m][q2][lane] +
                            red1[2][m][q2][lane] + red1[3][m][q2][lane];
                facbuf[(size_t)(m * 16 + h) * T_DIM + qbase + 16 * q2 + lane] = mw / tot;
            }
        }
    }
}

// ---------------- Pass 2: combined-P PV + RMS + subln, QT=32 rows/block.
__global__ __launch_bounds__(256) void attn_pv(const u16* __restrict__ qb,
                                               const u16* __restrict__ kpack,
                                               const u16* __restrict__ vpack,
                                               const float* __restrict__ facbuf,
                                               const float* __restrict__ subln,
                                               u16* __restrict__ outb) {
    __shared__ __align__(16) char smem[12288];   // union: plds 10240B / red2 12288B
    const int tid = threadIdx.x;
    const int lane = tid & 63;
    const int wv = tid >> 6;
    const int col = lane & 15;
    const int g = lane >> 4;
    int h, qbase;
    attn_block_map(blockIdx.y * 64 + blockIdx.x, h, qbase);
    const int kvh = h >> 1;
    const int nfull = qbase >> 5;

    u16 (*plds)[2][16][40] = (u16(*)[2][16][40])smem;   // [wave][q2][qrow][key+pad]
    float (*red2)[48] = (float(*)[48])smem;             // [lane][48]

    bf16x8 qfrag[3][2];
#pragma unroll
    for (int m = 0; m < 3; ++m)
#pragma unroll
        for (int q2 = 0; q2 < 2; ++q2)
            qfrag[m][q2] = *(const bf16x8*)(qb + (size_t)(qbase + 16 * q2 + col) * E_DIM + m * 512 + h * 32 + 8 * g);

    float fac[3][2];
#pragma unroll
    for (int m = 0; m < 3; ++m)
#pragma unroll
        for (int q2 = 0; q2 < 2; ++q2)
            fac[m][q2] = facbuf[(size_t)(m * 16 + h) * T_DIM + qbase + 16 * q2 + col];

    f32x4 oacc[2][6];
#pragma unroll
    for (int q2 = 0; q2 < 2; ++q2)
#pragma unroll
        for (int ft = 0; ft < 6; ++ft) oacc[q2][ft] = (f32x4){0.f, 0.f, 0.f, 0.f};

    const int laneoff = col * 32 + 8 * g;
    const u16* kt = kpack + (size_t)(kvh * 64 + wv) * 3072;
    const u16* vt = vpack + (size_t)(kvh * 64 + wv) * 3072;

    for (int c = wv; c < nfull; c += 4) {
        bf16x8 kf[6], vf[6];
#pragma unroll
        for (int u = 0; u < 6; ++u) kf[u] = *(const bf16x8*)(kt + laneoff + u * 512);
#pragma unroll
        for (int u = 0; u < 6; ++u) vf[u] = *(const bf16x8*)(vt + laneoff + u * 512);
        kt += 4 * 3072;
        vt += 4 * 3072;

        __builtin_amdgcn_s_setprio(1);
#pragma unroll
        for (int q2 = 0; q2 < 2; ++q2)
#pragma unroll
            for (int st = 0; st < 2; ++st) {
                float pp[4] = {0.f, 0.f, 0.f, 0.f};
#pragma unroll
                for (int m = 0; m < 3; ++m) {
                    f32x4 sv = __builtin_amdgcn_mfma_f32_16x16x32_bf16(
                        kf[m * 2 + st], qfrag[m][q2], (f32x4){0.f, 0.f, 0.f, 0.f}, 0, 0, 0);
#pragma unroll
                    for (int r = 0; r < 4; ++r)
                        pp[r] += fac[m][q2] * __builtin_amdgcn_exp2f(sv[r]);
                }
                __hip_bfloat162 b01 = __float22bfloat162_rn(make_float2(pp[0], pp[1]));
                __hip_bfloat162 b23 = __float22bfloat162_rn(make_float2(pp[2], pp[3]));
                uint2 w;
                w.x = *(u32*)&b01;
                w.y = *(u32*)&b23;
                *(uint2*)&plds[wv][q2][col][st * 16 + 4 * g] = w;
            }
#pragma unroll
        for (int q2 = 0; q2 < 2; ++q2) {
            bf16x8 pf = *(const bf16x8*)&plds[wv][q2][col][8 * g];
#pragma unroll
            for (int ft = 0; ft < 6; ++ft)
                oacc[q2][ft] = __builtin_amdgcn_mfma_f32_16x16x32_bf16(pf, vf[ft], oacc[q2][ft], 0, 0, 0);
        }
        __builtin_amdgcn_s_setprio(0);
    }

    // boundary chunk: q2=0 -> st0 triangular, st1 zeros; q2=1 -> st0 full, st1 triangular.
    if ((nfull & 3) == wv) {
        const u16* ktm = kpack + (size_t)(kvh * 64 + nfull) * 3072 + laneoff;
        const u16* vtm = vpack + (size_t)(kvh * 64 + nfull) * 3072 + laneoff;
        bf16x8 kf[6], vf[6];
#pragma unroll
        for (int u = 0; u < 6; ++u) kf[u] = *(const bf16x8*)(ktm + u * 512);
#pragma unroll
        for (int u = 0; u < 6; ++u) vf[u] = *(const bf16x8*)(vtm + u * 512);

        {
            float pp[4] = {0.f, 0.f, 0.f, 0.f};
#pragma unroll
            for (int m = 0; m < 3; ++m) {
                f32x4 sv = __builtin_amdgcn_mfma_f32_16x16x32_bf16(
                    kf[m * 2 + 0], qfrag[m][0], (f32x4){0.f, 0.f, 0.f, 0.f}, 0, 0, 0);
#pragma unroll
                for (int r = 0; r < 4; ++r) {
                    float x = (4 * g + r > col) ? -1e30f : sv[r];
                    pp[r] += fac[m][0] * __builtin_amdgcn_exp2f(x);
                }
            }
            __hip_bfloat162 b01 = __float22bfloat162_rn(make_float2(pp[0], pp[1]));
            __hip_bfloat162 b23 = __float22bfloat162_rn(make_float2(pp[2], pp[3]));
            uint2 w;
            w.x = *(u32*)&b01;
            w.y = *(u32*)&b23;
            *(uint2*)&plds[wv][0][col][4 * g] = w;
            uint2 z = make_uint2(0u, 0u);
            *(uint2*)&plds[wv][0][col][16 + 4 * g] = z;
        }
        {
            float p0[4] = {0.f, 0.f, 0.f, 0.f};
            float p1[4] = {0.f, 0.f, 0.f, 0.f};
#pragma unroll
            for (int m = 0; m < 3; ++m) {
                f32x4 sv0 = __builtin_amdgcn_mfma_f32_16x16x32_bf16(
                    kf[m * 2 + 0], qfrag[m][1], (f32x4){0.f, 0.f, 0.f, 0.f}, 0, 0, 0);
                f32x4 sv1 = __builtin_amdgcn_mfma_f32_16x16x32_bf16(
                    kf[m * 2 + 1], qfrag[m][1], (f32x4){0.f, 0.f, 0.f, 0.f}, 0, 0, 0);
#pragma unroll
                for (int r = 0; r < 4; ++r) {
                    p0[r] += fac[m][1] * __builtin_amdgcn_exp2f(sv0[r]);
                    float x = (4 * g + r > col) ? -1e30f : sv1[r];
                    p1[r] += fac[m][1] * __builtin_amdgcn_exp2f(x);
                }
            }
            __hip_bfloat162 a01 = __float22bfloat162_rn(make_float2(p0[0], p0[1]));
            __hip_bfloat162 a23 = __float22bfloat162_rn(make_float2(p0[2], p0[3]));
            uint2 w0;
            w0.x = *(u32*)&a01;
            w0.y = *(u32*)&a23;
            *(uint2*)&plds[wv][1][col][4 * g] = w0;
            __hip_bfloat162 b01 = __float22bfloat162_rn(make_float2(p1[0], p1[1]));
            __hip_bfloat162 b23 = __float22bfloat162_rn(make_float2(p1[2], p1[3]));
            uint2 w1;
            w1.x = *(u32*)&b01;
            w1.y = *(u32*)&b23;
            *(uint2*)&plds[wv][1][col][16 + 4 * g] = w1;
        }
#pragma unroll
        for (int q2 = 0; q2 < 2; ++q2) {
            bf16x8 pf = *(const bf16x8*)&plds[wv][q2][col][8 * g];
#pragma unroll
            for (int ft = 0; ft < 6; ++ft)
                oacc[q2][ft] = __builtin_amdgcn_mfma_f32_16x16x32_bf16(pf, vf[ft], oacc[q2][ft], 0, 0, 0);
        }
    }

    // ---- cross-wave reduce: sequential rounds through the union buffer
    __syncthreads();
#pragma unroll
    for (int src = 1; src < 4; ++src) {
        if (wv == src) {
            float4* rp = (float4*)red2[lane];
#pragma unroll
            for (int q2 = 0; q2 < 2; ++q2)
#pragma unroll
                for (int ft = 0; ft < 6; ++ft)
                    rp[q2 * 6 + ft] = make_float4(oacc[q2][ft][0], oacc[q2][ft][1],
                                                  oacc[q2][ft][2], oacc[q2][ft][3]);
        }
        __syncthreads();
        if (wv == 0) {
            const float4* rp = (const float4*)red2[lane];
#pragma unroll
            for (int q2 = 0; q2 < 2; ++q2)
#pragma unroll
                for (int ft = 0; ft < 6; ++ft) {
                    float4 a = rp[q2 * 6 + ft];
                    oacc[q2][ft][0] += a.x; oacc[q2][ft][1] += a.y;
                    oacc[q2][ft][2] += a.z; oacc[q2][ft][3] += a.w;
                }
        }
        __syncthreads();
    }
    if (wv != 0) return;

    // ---- epilogue: RMS + subln (fac already folded into P)
    float ss[2][4] = {{0.f, 0.f, 0.f, 0.f}, {0.f, 0.f, 0.f, 0.f}};
#pragma unroll
    for (int q2 = 0; q2 < 2; ++q2)
#pragma unroll
        for (int ft = 0; ft < 6; ++ft)
#pragma unroll
            for (int r = 0; r < 4; ++r) ss[q2][r] += oacc[q2][ft][r] * oacc[q2][ft][r];
#pragma unroll
    for (int q2 = 0; q2 < 2; ++q2)
#pragma unroll
        for (int r = 0; r < 4; ++r) {
            ss[q2][r] += __shfl_xor(ss[q2][r], 1, 64);
            ss[q2][r] += __shfl_xor(ss[q2][r], 2, 64);
            ss[q2][r] += __shfl_xor(ss[q2][r], 4, 64);
            ss[q2][r] += __shfl_xor(ss[q2][r], 8, 64);
            ss[q2][r] = rsqrtf(ss[q2][r] * (1.f / 96.f) + 1e-5f);
        }
#pragma unroll
    for (int ft = 0; ft < 6; ++ft) {
        float sl = subln[ft * 16 + col];
#pragma unroll
        for (int q2 = 0; q2 < 2; ++q2)
#pragma unroll
            for (int r = 0; r < 4; ++r) {
                int trow = qbase + 16 * q2 + 4 * g + r;
                outb[(size_t)trow * E_DIM + h * 96 + ft * 16 + col] = f2bf(oacc[q2][ft][r] * ss[q2][r] * sl);
            }
    }
}

extern "C" void kernel_launch(void* const* d_in, const int* in_sizes, int n_in,
                              void* d_out, int out_size, void* d_ws, size_t ws_size,
                              hipStream_t stream) {
    const float* x       = (const float*)d_in[0];
    const float* cosb    = (const float*)d_in[1];
    const float* sinb    = (const float*)d_in[2];
    const float* q_w     = (const float*)d_in[3];
    const float* k_w     = (const float*)d_in[4];
    const float* v_w     = (const float*)d_in[5];
    const float* out_w   = (const float*)d_in[6];
    const float* raw_map = (const float*)d_in[7];
    const float* wscale  = (const float*)d_in[8];
    const float* subln   = (const float*)d_in[9];
    float* out = (float*)d_out;

    char* ws = (char*)d_ws;
    u16* xb16   = (u16*)(ws);                    // 2048x1536  (6,291,456 B)  [ab16 alias later]
    u16* wqkv16 = (u16*)(ws + 6291456);          // 3072x1536  (9,437,184 B)
    u16* qb16   = (u16*)(ws + 15728640);         // 2048x1536  (6,291,456 B)
    u16* kpack  = (u16*)(ws + 22020096);         // 8x64x3x2x16x32 (3,145,728 B) + pad
    u16* vpack  = (u16*)(ws + 25190400);         // 8x64x96x32     (3,145,728 B) + pad
    u16* wout16 = (u16*)(ws + 28360704);         // 1536x1536  (4,718,592 B)
    float* facbuf = (float*)(ws + 33079296);     // 3x16x2048 f32 (393,216 B) -> ends 33,472,512
    u16* ab16   = xb16;                          // alias: x dead after QKV gemm

    // all f32 -> bf16 conversions in one launch
    cvt_bf16_5<<<9984, 256, 0, stream>>>(x, xb16,
                                         q_w, wqkv16,
                                         k_w, wqkv16 + 2359296,
                                         v_w, wqkv16 + 3538944,
                                         out_w, wout16);

    // fused QKV projection + RoPE + pack (128x64 tile, 768 blocks = 3/CU balanced).
    const float qscale = 0.17677669529663687f * 1.4426950408889634f;
    gemm_qkv_fused<<<dim3(3072 / 64, T_DIM / 128), 256, 0, stream>>>(
        xb16, wqkv16, cosb, sinb, qb16, kpack, vpack, qscale);

    // attention pass 1: softmax denominators -> fac (per head)
    attn_lsum<<<dim3(64, 16), 256, 0, stream>>>(qb16, kpack, raw_map, wscale, facbuf);

    // attention pass 2: combined-P PV + RMS + subln -> bf16
    attn_pv<<<dim3(64, 16), 256, 0, stream>>>(qb16, kpack, vpack, facbuf, subln, ab16);

    // output projection: [2048,1536] x [1536,1536]^T -> f32 d_out
    gemm_mfma_out<<<dim3(E_DIM / 64, T_DIM / 128), 256, 0, stream>>>(ab16, wout16, out, K_DIM, E_DIM);
}

// Round 22
// 118.574 us; speedup vs baseline: 1.0372x; 1.0372x over previous
//
#include <hip/hip_runtime.h>
#include <hip/hip_bf16.h>
#include <math.h>

#define T_DIM 2048
#define E_DIM 1536
#define K_DIM 1536

typedef unsigned short u16;
typedef unsigned int u32;
typedef __attribute__((ext_vector_type(8))) short bf16x8;
typedef __attribute__((ext_vector_type(4))) float f32x4;

__device__ __forceinline__ u16 f2bf(float x) {
    unsigned u = __float_as_uint(x);
    return (u16)((u + 0x7fffu + ((u >> 16) & 1u)) >> 16);
}

#define GLOAD16(gsrc, ldst)                                                              \
    __builtin_amdgcn_global_load_lds((const __attribute__((address_space(1))) u32*)(gsrc), \
                                     (__attribute__((address_space(3))) u32*)(ldst), 16, 0, 0)

// ---------------- all f32 -> bf16 conversions in ONE kernel (5 segments)
__global__ __launch_bounds__(256) void cvt_bf16_5(const float* __restrict__ s0, u16* __restrict__ d0,
                                                  const float* __restrict__ s1, u16* __restrict__ d1,
                                                  const float* __restrict__ s2, u16* __restrict__ d2,
                                                  const float* __restrict__ s3, u16* __restrict__ d3,
                                                  const float* __restrict__ s4, u16* __restrict__ d4) {
    int i = blockIdx.x * 256 + threadIdx.x;
    const float* s;
    u16* d;
    int off;
    if (i < 786432)       { s = s0; d = d0; off = i; }
    else if (i < 1376256) { s = s1; d = d1; off = i - 786432; }
    else if (i < 1671168) { s = s2; d = d2; off = i - 1376256; }
    else if (i < 1966080) { s = s3; d = d3; off = i - 1671168; }
    else                  { s = s4; d = d4; off = i - 1966080; }
    float4 v = ((const float4*)s)[off];
    ((ushort4*)d)[off] = make_ushort4(f2bf(v.x), f2bf(v.y), f2bf(v.z), f2bf(v.w));
}

// ---------------- fused QKV GEMM, 128x64 tile (768 blocks = 3/CU, balanced).
__global__ __launch_bounds__(256) void gemm_qkv_fused(const u16* __restrict__ A,
                                                      const u16* __restrict__ W,
                                                      const float* __restrict__ cosb,
                                                      const float* __restrict__ sinb,
                                                      u16* __restrict__ qb16,
                                                      u16* __restrict__ kpack,
                                                      u16* __restrict__ vpack,
                                                      float qscale) {
    const int K = K_DIM;
    __shared__ __align__(16) u16 As[128 * 64];
    __shared__ __align__(16) u16 Bs[64 * 64];
    const int tid = threadIdx.x;
    const int lane = tid & 63;
    const int wv = tid >> 6;
    const int wr = wv >> 1;
    const int wc = wv & 1;
    const int cl = lane & 15;
    const int g = lane >> 4;
    const int bm = blockIdx.y * 128;
    const int bn = blockIdx.x * 64;

    const char* Ab = (const char*)A;
    const char* Wb = (const char*)W;

    size_t a_src[4];
    int a_dst[4];
#pragma unroll
    for (int is = 0; is < 4; ++is) {
        int b = is * 4096 + wv * 1024 + lane * 16;
        int row = b >> 7;
        int wi = b & 127;
        a_src[is] = (size_t)(bm + row) * (K * 2) + (wi ^ ((row & 7) << 4));
        a_dst[is] = b;
    }
    size_t b_src[2];
    int b_dst[2];
#pragma unroll
    for (int is = 0; is < 2; ++is) {
        int b = is * 4096 + wv * 1024 + lane * 16;
        int row = b >> 7;
        int wi = b & 127;
        b_src[is] = (size_t)(bn + row) * (K * 2) + (wi ^ ((row & 7) << 4));
        b_dst[is] = b;
    }

    f32x4 acc[4][2];
#pragma unroll
    for (int mi = 0; mi < 4; ++mi)
#pragma unroll
        for (int ni = 0; ni < 2; ++ni) acc[mi][ni] = (f32x4){0.f, 0.f, 0.f, 0.f};

    for (int k0b = 0; k0b < K * 2; k0b += 128) {
#pragma unroll
        for (int is = 0; is < 4; ++is)
            GLOAD16(Ab + a_src[is] + k0b, (char*)As + a_dst[is]);
#pragma unroll
        for (int is = 0; is < 2; ++is)
            GLOAD16(Wb + b_src[is] + k0b, (char*)Bs + b_dst[is]);
        __syncthreads();
#pragma unroll
        for (int kk = 0; kk < 2; ++kk) {
            const int co = (kk * 64 + g * 16) ^ ((cl & 7) << 4);
            bf16x8 af[4], bfr[2];
#pragma unroll
            for (int mi = 0; mi < 4; ++mi)
                af[mi] = *(const bf16x8*)((const char*)As + (wr * 64 + mi * 16 + cl) * 128 + co);
#pragma unroll
            for (int ni = 0; ni < 2; ++ni)
                bfr[ni] = *(const bf16x8*)((const char*)Bs + (wc * 32 + ni * 16 + cl) * 128 + co);
#pragma unroll
            for (int mi = 0; mi < 4; ++mi)
#pragma unroll
                for (int ni = 0; ni < 2; ++ni)
                    acc[mi][ni] = __builtin_amdgcn_mfma_f32_16x16x32_bf16(af[mi], bfr[ni], acc[mi][ni], 0, 0, 0);
        }
        __syncthreads();
    }

    // ---- fused epilogue: RoPE + pack. col parity partner lives in lane^1.
    if (bn < 1536) {
#pragma unroll
        for (int mi = 0; mi < 4; ++mi)
#pragma unroll
            for (int ni = 0; ni < 2; ++ni)
#pragma unroll
                for (int r = 0; r < 4; ++r) {
                    int trow = bm + wr * 64 + mi * 16 + 4 * g + r;
                    int c = bn + wc * 32 + ni * 16 + cl;
                    float v = acc[mi][ni][r];
                    float pv = __shfl_xor(v, 1, 64);
                    int i = (c & 31) >> 1;
                    float cs = cosb[trow * 16 + i];
                    float sn = sinb[trow * 16 + i];
                    float o = v * cs + ((c & 1) ? pv * sn : -pv * sn);
                    qb16[(size_t)trow * E_DIM + c] = f2bf(o * qscale);
                }
    } else if (bn < 2304) {
#pragma unroll
        for (int mi = 0; mi < 4; ++mi)
#pragma unroll
            for (int ni = 0; ni < 2; ++ni)
#pragma unroll
                for (int r = 0; r < 4; ++r) {
                    int trow = bm + wr * 64 + mi * 16 + 4 * g + r;
                    int c = bn + wc * 32 + ni * 16 + cl;
                    float v = acc[mi][ni][r];
                    float pv = __shfl_xor(v, 1, 64);
                    int i = (c & 31) >> 1;
                    float cs = cosb[trow * 16 + i];
                    float sn = sinb[trow * 16 + i];
                    float o = v * cs + ((c & 1) ? pv * sn : -pv * sn);
                    int ck = c - 1536;
                    int m = ck >> 8;
                    int rem = ck & 255;
                    int kvhh = rem >> 5;
                    int d = rem & 31;
                    int cch = trow >> 5, st2 = (trow >> 4) & 1, colk = trow & 15;
                    size_t dstb = ((((size_t)(kvhh * 64 + cch) * 3 + m) * 2 + st2) * 16 + colk) * 32 + d;
                    kpack[dstb] = f2bf(o);
                }
    } else {
#pragma unroll
        for (int mi = 0; mi < 4; ++mi)
#pragma unroll
            for (int ni = 0; ni < 2; ++ni)
#pragma unroll
                for (int r = 0; r < 4; ++r) {
                    int trow = bm + wr * 64 + mi * 16 + 4 * g + r;
                    int c = bn + wc * 32 + ni * 16 + cl;
                    int fq = c - 2304;
                    int kvhh = fq / 96;
                    int f = fq - kvhh * 96;
                    size_t dstb = ((size_t)(kvhh * 64 + (trow >> 5)) * 96 + f) * 32 + (trow & 31);
                    vpack[dstb] = f2bf(acc[mi][ni][r]);
                }
    }
}

// ---------------- bf16 MFMA GEMM 64x64 tile (output projection; 768 blocks = 3/CU).
__global__ __launch_bounds__(256) void gemm_mfma_out(const u16* __restrict__ A,
                                                     const u16* __restrict__ W,
                                                     float* __restrict__ Cp,
                                                     int K, int ldC) {
    __shared__ __align__(16) u16 As[64 * 64];
    __shared__ __align__(16) u16 Bs[64 * 64];
    const int tid = threadIdx.x;
    const int lane = tid & 63;
    const int wv = tid >> 6;
    const int wr = wv >> 1;
    const int wc = wv & 1;
    const int cl = lane & 15;
    const int g = lane >> 4;
    const int bm = blockIdx.y * 64;
    const int bn = blockIdx.x * 64;

    const char* Ab = (const char*)A;
    const char* Wb = (const char*)W;

    size_t a_src[2], b_src[2];
    int dst2[2];
#pragma unroll
    for (int is = 0; is < 2; ++is) {
        int b = is * 4096 + tid * 16;
        int row = b >> 7;
        int wi = b & 127;
        dst2[is] = b;
        a_src[is] = (size_t)(bm + row) * (K * 2) + (wi ^ ((row & 7) << 4));
        b_src[is] = (size_t)(bn + row) * (K * 2) + (wi ^ ((row & 7) << 4));
    }

    f32x4 acc[2][2];
#pragma unroll
    for (int mi = 0; mi < 2; ++mi)
#pragma unroll
        for (int ni = 0; ni < 2; ++ni) acc[mi][ni] = (f32x4){0.f, 0.f, 0.f, 0.f};

    for (int k0b = 0; k0b < K * 2; k0b += 128) {
#pragma unroll
        for (int is = 0; is < 2; ++is)
            GLOAD16(Ab + a_src[is] + k0b, (char*)As + dst2[is]);
#pragma unroll
        for (int is = 0; is < 2; ++is)
            GLOAD16(Wb + b_src[is] + k0b, (char*)Bs + dst2[is]);
        __syncthreads();
#pragma unroll
        for (int kk = 0; kk < 2; ++kk) {
            const int co = (kk * 64 + g * 16) ^ ((cl & 7) << 4);
            bf16x8 af[2], bfr[2];
#pragma unroll
            for (int mi = 0; mi < 2; ++mi)
                af[mi] = *(const bf16x8*)((const char*)As + (wr * 32 + mi * 16 + cl) * 128 + co);
#pragma unroll
            for (int ni = 0; ni < 2; ++ni)
                bfr[ni] = *(const bf16x8*)((const char*)Bs + (wc * 32 + ni * 16 + cl) * 128 + co);
#pragma unroll
            for (int mi = 0; mi < 2; ++mi)
#pragma unroll
                for (int ni = 0; ni < 2; ++ni)
                    acc[mi][ni] = __builtin_amdgcn_mfma_f32_16x16x32_bf16(af[mi], bfr[ni], acc[mi][ni], 0, 0, 0);
        }
        __syncthreads();
    }

#pragma unroll
    for (int mi = 0; mi < 2; ++mi)
#pragma unroll
        for (int ni = 0; ni < 2; ++ni)
#pragma unroll
            for (int r = 0; r < 4; ++r) {
                size_t row = bm + wr * 32 + mi * 16 + 4 * g + r;
                size_t col = bn + wc * 32 + ni * 16 + cl;
                Cp[row * ldC + col] = acc[mi][ni][r];
            }
}

// XCD-affinity block remap (simple LPT).
__device__ __forceinline__ void attn_block_map(int lid, int& h, int& qbase) {
    int kvh8 = lid & 7;
    int rest = lid >> 3;
    h = kvh8 * 2 + (rest & 1);
    qbase = (63 - (rest >> 1)) * 32;
}

// ---------------- Pass 1: softmax denominators, QT=32 rows/block.
__global__ __launch_bounds__(256) void attn_lsum(const u16* __restrict__ qb,
                                                 const u16* __restrict__ kpack,
                                                 const float* __restrict__ raw_map,
                                                 const float* __restrict__ wscale,
                                                 float* __restrict__ facbuf) {
    __shared__ float red1[4][3][2][16];
    const int tid = threadIdx.x;
    const int lane = tid & 63;
    const int wv = tid >> 6;
    const int col = lane & 15;
    const int g = lane >> 4;
    int h, qbase;
    attn_block_map(blockIdx.y * 64 + blockIdx.x, h, qbase);
    const int kvh = h >> 1;
    const int nfull = qbase >> 5;

    bf16x8 qfrag[3][2];
#pragma unroll
    for (int m = 0; m < 3; ++m)
#pragma unroll
        for (int q2 = 0; q2 < 2; ++q2)
            qfrag[m][q2] = *(const bf16x8*)(qb + (size_t)(qbase + 16 * q2 + col) * E_DIM + m * 512 + h * 32 + 8 * g);

    float lsum[3][2] = {{0.f, 0.f}, {0.f, 0.f}, {0.f, 0.f}};
    const int laneoff = col * 32 + 8 * g;
    const u16* kt = kpack + (size_t)(kvh * 64 + wv) * 3072;

    for (int c = wv; c < nfull; c += 4) {
        bf16x8 kf[6];
#pragma unroll
        for (int u = 0; u < 6; ++u) kf[u] = *(const bf16x8*)(kt + laneoff + u * 512);
        kt += 4 * 3072;
        __builtin_amdgcn_s_setprio(1);
#pragma unroll
        for (int m = 0; m < 3; ++m)
#pragma unroll
            for (int st = 0; st < 2; ++st)
#pragma unroll
                for (int q2 = 0; q2 < 2; ++q2) {
                    f32x4 sv = __builtin_amdgcn_mfma_f32_16x16x32_bf16(
                        kf[m * 2 + st], qfrag[m][q2], (f32x4){0.f, 0.f, 0.f, 0.f}, 0, 0, 0);
                    lsum[m][q2] += (__builtin_amdgcn_exp2f(sv[0]) + __builtin_amdgcn_exp2f(sv[1])) +
                                   (__builtin_amdgcn_exp2f(sv[2]) + __builtin_amdgcn_exp2f(sv[3]));
                }
        __builtin_amdgcn_s_setprio(0);
    }

    if ((nfull & 3) == wv) {
        const u16* ktm = kpack + (size_t)(kvh * 64 + nfull) * 3072 + laneoff;
        bf16x8 kf[6];
#pragma unroll
        for (int u = 0; u < 6; ++u) kf[u] = *(const bf16x8*)(ktm + u * 512);
#pragma unroll
        for (int m = 0; m < 3; ++m) {
            {
                f32x4 sv = __builtin_amdgcn_mfma_f32_16x16x32_bf16(
                    kf[m * 2 + 0], qfrag[m][0], (f32x4){0.f, 0.f, 0.f, 0.f}, 0, 0, 0);
#pragma unroll
                for (int r = 0; r < 4; ++r) {
                    float x = (4 * g + r > col) ? -1e30f : sv[r];
                    lsum[m][0] += __builtin_amdgcn_exp2f(x);
                }
            }
            {
                f32x4 sv = __builtin_amdgcn_mfma_f32_16x16x32_bf16(
                    kf[m * 2 + 0], qfrag[m][1], (f32x4){0.f, 0.f, 0.f, 0.f}, 0, 0, 0);
                lsum[m][1] += (__builtin_amdgcn_exp2f(sv[0]) + __builtin_amdgcn_exp2f(sv[1])) +
                              (__builtin_amdgcn_exp2f(sv[2]) + __builtin_amdgcn_exp2f(sv[3]));
            }
            {
                f32x4 sv = __builtin_amdgcn_mfma_f32_16x16x32_bf16(
                    kf[m * 2 + 1], qfrag[m][1], (f32x4){0.f, 0.f, 0.f, 0.f}, 0, 0, 0);
#pragma unroll
                for (int r = 0; r < 4; ++r) {
                    float x = (4 * g + r > col) ? -1e30f : sv[r];
                    lsum[m][1] += __builtin_amdgcn_exp2f(x);
                }
            }
        }
    }

#pragma unroll
    for (int m = 0; m < 3; ++m)
#pragma unroll
        for (int q2 = 0; q2 < 2; ++q2) {
            lsum[m][q2] += __shfl_xor(lsum[m][q2], 16, 64);
            lsum[m][q2] += __shfl_xor(lsum[m][q2], 32, 64);
        }
    if (g == 0) {
#pragma unroll
        for (int m = 0; m < 3; ++m)
#pragma unroll
            for (int q2 = 0; q2 < 2; ++q2) red1[wv][m][q2][col] = lsum[m][q2];
    }
    __syncthreads();
    if (wv == 0 && lane < 16) {
        float wsc = wscale[0];
#pragma unroll
        for (int m = 0; m < 3; ++m) {
            float mw = tanhf(raw_map[m]) * wsc;
#pragma unroll
            for (int q2 = 0; q2 < 2; ++q2) {
                float tot = red1[0][m][q2][lane] + red1[1][m][q2][lane] +
                            red1[2][m][q2][lane] + red1[3][m][q2][lane];
                facbuf[(size_t)(m * 16 + h) * T_DIM + qbase + 16 * q2 + lane] = mw / tot;
            }
        }
    }
}

// ---------------- Pass 2: combined-P PV + RMS + subln, QT=32 rows/block.
__global__ __launch_bounds__(256) void attn_pv(const u16* __restrict__ qb,
                                               const u16* __restrict__ kpack,
                                               const u16* __restrict__ vpack,
                                               const float* __restrict__ facbuf,
                                               const float* __restrict__ subln,
                                               u16* __restrict__ outb) {
    __shared__ __align__(16) char smem[12288];   // union: plds 10240B / red2 12288B
    const int tid = threadIdx.x;
    const int lane = tid & 63;
    const int wv = tid >> 6;
    const int col = lane & 15;
    const int g = lane >> 4;
    int h, qbase;
    attn_block_map(blockIdx.y * 64 + blockIdx.x, h, qbase);
    const int kvh = h >> 1;
    const int nfull = qbase >> 5;

    u16 (*plds)[2][16][40] = (u16(*)[2][16][40])smem;
    float (*red2)[48] = (float(*)[48])smem;

    bf16x8 qfrag[3][2];
#pragma unroll
    for (int m = 0; m < 3; ++m)
#pragma unroll
        for (int q2 = 0; q2 < 2; ++q2)
            qfrag[m][q2] = *(const bf16x8*)(qb + (size_t)(qbase + 16 * q2 + col) * E_DIM + m * 512 + h * 32 + 8 * g);

    float fac[3][2];
#pragma unroll
    for (int m = 0; m < 3; ++m)
#pragma unroll
        for (int q2 = 0; q2 < 2; ++q2)
            fac[m][q2] = facbuf[(size_t)(m * 16 + h) * T_DIM + qbase + 16 * q2 + col];

    f32x4 oacc[2][6];
#pragma unroll
    for (int q2 = 0; q2 < 2; ++q2)
#pragma unroll
        for (int ft = 0; ft < 6; ++ft) oacc[q2][ft] = (f32x4){0.f, 0.f, 0.f, 0.f};

    const int laneoff = col * 32 + 8 * g;
    const u16* kt = kpack + (size_t)(kvh * 64 + wv) * 3072;
    const u16* vt = vpack + (size_t)(kvh * 64 + wv) * 3072;

    for (int c = wv; c < nfull; c += 4) {
        bf16x8 kf[6], vf[6];
#pragma unroll
        for (int u = 0; u < 6; ++u) kf[u] = *(const bf16x8*)(kt + laneoff + u * 512);
#pragma unroll
        for (int u = 0; u < 6; ++u) vf[u] = *(const bf16x8*)(vt + laneoff + u * 512);
        kt += 4 * 3072;
        vt += 4 * 3072;

        __builtin_amdgcn_s_setprio(1);
#pragma unroll
        for (int q2 = 0; q2 < 2; ++q2)
#pragma unroll
            for (int st = 0; st < 2; ++st) {
                float pp[4] = {0.f, 0.f, 0.f, 0.f};
#pragma unroll
                for (int m = 0; m < 3; ++m) {
                    f32x4 sv = __builtin_amdgcn_mfma_f32_16x16x32_bf16(
                        kf[m * 2 + st], qfrag[m][q2], (f32x4){0.f, 0.f, 0.f, 0.f}, 0, 0, 0);
#pragma unroll
                    for (int r = 0; r < 4; ++r)
                        pp[r] += fac[m][q2] * __builtin_amdgcn_exp2f(sv[r]);
                }
                __hip_bfloat162 b01 = __float22bfloat162_rn(make_float2(pp[0], pp[1]));
                __hip_bfloat162 b23 = __float22bfloat162_rn(make_float2(pp[2], pp[3]));
                uint2 w;
                w.x = *(u32*)&b01;
                w.y = *(u32*)&b23;
                *(uint2*)&plds[wv][q2][col][st * 16 + 4 * g] = w;
            }
#pragma unroll
        for (int q2 = 0; q2 < 2; ++q2) {
            bf16x8 pf = *(const bf16x8*)&plds[wv][q2][col][8 * g];
#pragma unroll
            for (int ft = 0; ft < 6; ++ft)
                oacc[q2][ft] = __builtin_amdgcn_mfma_f32_16x16x32_bf16(pf, vf[ft], oacc[q2][ft], 0, 0, 0);
        }
        __builtin_amdgcn_s_setprio(0);
    }

    // boundary chunk: q2=0 -> st0 triangular, st1 zeros; q2=1 -> st0 full, st1 triangular.
    if ((nfull & 3) == wv) {
        const u16* ktm = kpack + (size_t)(kvh * 64 + nfull) * 3072 + laneoff;
        const u16* vtm = vpack + (size_t)(kvh * 64 + nfull) * 3072 + laneoff;
        bf16x8 kf[6], vf[6];
#pragma unroll
        for (int u = 0; u < 6; ++u) kf[u] = *(const bf16x8*)(ktm + u * 512);
#pragma unroll
        for (int u = 0; u < 6; ++u) vf[u] = *(const bf16x8*)(vtm + u * 512);

        {
            float pp[4] = {0.f, 0.f, 0.f, 0.f};
#pragma unroll
            for (int m = 0; m < 3; ++m) {
                f32x4 sv = __builtin_amdgcn_mfma_f32_16x16x32_bf16(
                    kf[m * 2 + 0], qfrag[m][0], (f32x4){0.f, 0.f, 0.f, 0.f}, 0, 0, 0);
#pragma unroll
                for (int r = 0; r < 4; ++r) {
                    float x = (4 * g + r > col) ? -1e30f : sv[r];
                    pp[r] += fac[m][0] * __builtin_amdgcn_exp2f(x);
                }
            }
            __hip_bfloat162 b01 = __float22bfloat162_rn(make_float2(pp[0], pp[1]));
            __hip_bfloat162 b23 = __float22bfloat162_rn(make_float2(pp[2], pp[3]));
            uint2 w;
            w.x = *(u32*)&b01;
            w.y = *(u32*)&b23;
            *(uint2*)&plds[wv][0][col][4 * g] = w;
            uint2 z = make_uint2(0u, 0u);
            *(uint2*)&plds[wv][0][col][16 + 4 * g] = z;
        }
        {
            float p0[4] = {0.f, 0.f, 0.f, 0.f};
            float p1[4] = {0.f, 0.f, 0.f, 0.f};
#pragma unroll
            for (int m = 0; m < 3; ++m) {
                f32x4 sv0 = __builtin_amdgcn_mfma_f32_16x16x32_bf16(
                    kf[m * 2 + 0], qfrag[m][1], (f32x4){0.f, 0.f, 0.f, 0.f}, 0, 0, 0);
                f32x4 sv1 = __builtin_amdgcn_mfma_f32_16x16x32_bf16(
                    kf[m * 2 + 1], qfrag[m][1], (f32x4){0.f, 0.f, 0.f, 0.f}, 0, 0, 0);
#pragma unroll
                for (int r = 0; r < 4; ++r) {
                    p0[r] += fac[m][1] * __builtin_amdgcn_exp2f(sv0[r]);
                    float x = (4 * g + r > col) ? -1e30f : sv1[r];
                    p1[r] += fac[m][1] * __builtin_amdgcn_exp2f(x);
                }
            }
            __hip_bfloat162 a01 = __float22bfloat162_rn(make_float2(p0[0], p0[1]));
            __hip_bfloat162 a23 = __float22bfloat162_rn(make_float2(p0[2], p0[3]));
            uint2 w0;
            w0.x = *(u32*)&a01;
            w0.y = *(u32*)&a23;
            *(uint2*)&plds[wv][1][col][4 * g] = w0;
            __hip_bfloat162 b01 = __float22bfloat162_rn(make_float2(p1[0], p1[1]));
            __hip_bfloat162 b23 = __float22bfloat162_rn(make_float2(p1[2], p1[3]));
            uint2 w1;
            w1.x = *(u32*)&b01;
            w1.y = *(u32*)&b23;
            *(uint2*)&plds[wv][1][col][16 + 4 * g] = w1;
        }
#pragma unroll
        for (int q2 = 0; q2 < 2; ++q2) {
            bf16x8 pf = *(const bf16x8*)&plds[wv][q2][col][8 * g];
#pragma unroll
            for (int ft = 0; ft < 6; ++ft)
                oacc[q2][ft] = __builtin_amdgcn_mfma_f32_16x16x32_bf16(pf, vf[ft], oacc[q2][ft], 0, 0, 0);
        }
    }

    // ---- cross-wave reduce: sequential rounds through the union buffer
    __syncthreads();
#pragma unroll
    for (int src = 1; src < 4; ++src) {
        if (wv == src) {
            float4* rp = (float4*)red2[lane];
#pragma unroll
            for (int q2 = 0; q2 < 2; ++q2)
#pragma unroll
                for (int ft = 0; ft < 6; ++ft)
                    rp[q2 * 6 + ft] = make_float4(oacc[q2][ft][0], oacc[q2][ft][1],
                                                  oacc[q2][ft][2], oacc[q2][ft][3]);
        }
        __syncthreads();
        if (wv == 0) {
            const float4* rp = (const float4*)red2[lane];
#pragma unroll
            for (int q2 = 0; q2 < 2; ++q2)
#pragma unroll
                for (int ft = 0; ft < 6; ++ft) {
                    float4 a = rp[q2 * 6 + ft];
                    oacc[q2][ft][0] += a.x; oacc[q2][ft][1] += a.y;
                    oacc[q2][ft][2] += a.z; oacc[q2][ft][3] += a.w;
                }
        }
        __syncthreads();
    }
    if (wv != 0) return;

    // ---- epilogue: RMS + subln (fac already folded into P)
    float ss[2][4] = {{0.f, 0.f, 0.f, 0.f}, {0.f, 0.f, 0.f, 0.f}};
#pragma unroll
    for (int q2 = 0; q2 < 2; ++q2)
#pragma unroll
        for (int ft = 0; ft < 6; ++ft)
#pragma unroll
            for (int r = 0; r < 4; ++r) ss[q2][r] += oacc[q2][ft][r] * oacc[q2][ft][r];
#pragma unroll
    for (int q2 = 0; q2 < 2; ++q2)
#pragma unroll
        for (int r = 0; r < 4; ++r) {
            ss[q2][r] += __shfl_xor(ss[q2][r], 1, 64);
            ss[q2][r] += __shfl_xor(ss[q2][r], 2, 64);
            ss[q2][r] += __shfl_xor(ss[q2][r], 4, 64);
            ss[q2][r] += __shfl_xor(ss[q2][r], 8, 64);
            ss[q2][r] = rsqrtf(ss[q2][r] * (1.f / 96.f) + 1e-5f);
        }
#pragma unroll
    for (int ft = 0; ft < 6; ++ft) {
        float sl = subln[ft * 16 + col];
#pragma unroll
        for (int q2 = 0; q2 < 2; ++q2)
#pragma unroll
            for (int r = 0; r < 4; ++r) {
                int trow = qbase + 16 * q2 + 4 * g + r;
                outb[(size_t)trow * E_DIM + h * 96 + ft * 16 + col] = f2bf(oacc[q2][ft][r] * ss[q2][r] * sl);
            }
    }
}

extern "C" void kernel_launch(void* const* d_in, const int* in_sizes, int n_in,
                              void* d_out, int out_size, void* d_ws, size_t ws_size,
                              hipStream_t stream) {
    const float* x       = (const float*)d_in[0];
    const float* cosb    = (const float*)d_in[1];
    const float* sinb    = (const float*)d_in[2];
    const float* q_w     = (const float*)d_in[3];
    const float* k_w     = (const float*)d_in[4];
    const float* v_w     = (const float*)d_in[5];
    const float* out_w   = (const float*)d_in[6];
    const float* raw_map = (const float*)d_in[7];
    const float* wscale  = (const float*)d_in[8];
    const float* subln   = (const float*)d_in[9];
    float* out = (float*)d_out;

    char* ws = (char*)d_ws;
    u16* xb16   = (u16*)(ws);                    // 2048x1536  (6,291,456 B)  [ab16 alias later]
    u16* wqkv16 = (u16*)(ws + 6291456);          // 3072x1536  (9,437,184 B)
    u16* qb16   = (u16*)(ws + 15728640);         // 2048x1536  (6,291,456 B)
    u16* kpack  = (u16*)(ws + 22020096);         // 8x64x3x2x16x32 (3,145,728 B) + pad
    u16* vpack  = (u16*)(ws + 25190400);         // 8x64x96x32     (3,145,728 B) + pad
    u16* wout16 = (u16*)(ws + 28360704);         // 1536x1536  (4,718,592 B)
    float* facbuf = (float*)(ws + 33079296);     // 3x16x2048 f32 (393,216 B) -> ends 33,472,512
    u16* ab16   = xb16;                          // alias: x dead after QKV gemm

    // all f32 -> bf16 conversions in one launch
    cvt_bf16_5<<<9984, 256, 0, stream>>>(x, xb16,
                                         q_w, wqkv16,
                                         k_w, wqkv16 + 2359296,
                                         v_w, wqkv16 + 3538944,
                                         out_w, wout16);

    // fused QKV projection + RoPE + pack (128x64 tile, 768 blocks = 3/CU balanced).
    const float qscale = 0.17677669529663687f * 1.4426950408889634f;
    gemm_qkv_fused<<<dim3(3072 / 64, T_DIM / 128), 256, 0, stream>>>(
        xb16, wqkv16, cosb, sinb, qb16, kpack, vpack, qscale);

    // attention pass 1: softmax denominators -> fac (per head)
    attn_lsum<<<dim3(64, 16), 256, 0, stream>>>(qb16, kpack, raw_map, wscale, facbuf);

    // attention pass 2: combined-P PV + RMS + subln -> bf16
    attn_pv<<<dim3(64, 16), 256, 0, stream>>>(qb16, kpack, vpack, facbuf, subln, ab16);

    // output projection: [2048,1536] x [1536,1536]^T -> f32 d_out (64x64, 768 blocks)
    gemm_mfma_out<<<dim3(E_DIM / 64, T_DIM / 64), 256, 0, stream>>>(ab16, wout16, out, K_DIM, E_DIM);
}